// Round 7
// baseline (248.831 us; speedup 1.0000x reference)
//
#include <hip/hip_runtime.h>
#include <hip/hip_bf16.h>
#include <stdint.h>

typedef __bf16 bf16;
typedef __bf16 bf16x8 __attribute__((ext_vector_type(8)));
typedef float  f32x4  __attribute__((ext_vector_type(4)));
typedef float  f32x16 __attribute__((ext_vector_type(16)));
typedef unsigned int u32;
typedef u32 u32x4 __attribute__((ext_vector_type(4)));

static constexpr int S_LEN = 2048;
static constexpr int HIDN  = 2048;
static constexpr int BATCH = 2;
static constexpr int MTOT  = BATCH * S_LEN;   // 4096
static constexpr int NH    = 8;
static constexpr int DH    = 256;
static constexpr int NPAD  = 2688;            // 2612 proj cols padded to 21*128
static constexpr float QSCALE = 0.0625f / 6.0f;  // SCALING(1/16) * 1/RQ

__device__ __forceinline__ void gload16(const bf16* g, const bf16* l) {
  __builtin_amdgcn_global_load_lds(
      (const __attribute__((address_space(1))) void*)g,
      (__attribute__((address_space(3))) void*)l, 16, 0, 0);
}

// ---------------------------------------------------------------- casts
__global__ void cast_x_kernel(const float* __restrict__ in, bf16* __restrict__ out) {
  int i = blockIdx.x * blockDim.x + threadIdx.x;          // one thread per 8 elems
  const float4* p = reinterpret_cast<const float4*>(in) + 2 * (size_t)i;
  float4 a = p[0], b = p[1];
  bf16x8 o;
  o[0]=(bf16)a.x; o[1]=(bf16)a.y; o[2]=(bf16)a.z; o[3]=(bf16)a.w;
  o[4]=(bf16)b.x; o[5]=(bf16)b.y; o[6]=(bf16)b.z; o[7]=(bf16)b.w;
  reinterpret_cast<bf16x8*>(out)[i] = o;
}

__global__ void cast_w_kernel(const float* __restrict__ Wq, const float* __restrict__ Wk,
                              const float* __restrict__ Wv, const float* __restrict__ Bq,
                              const float* __restrict__ Bk, const float* __restrict__ Bv,
                              const float* __restrict__ Wo, bf16* __restrict__ Wcat,
                              bf16* __restrict__ Wob) {
  int row = blockIdx.x;
  int c = threadIdx.x * 8;
  const float* src = nullptr;
  bf16* dst;
  if (row < NPAD) {
    dst = Wcat + (size_t)row * HIDN;
    if      (row <   48) src = Wq + (size_t)row        * HIDN;
    else if (row <   50) src = Wk + (size_t)(row-  48) * HIDN;
    else if (row <   52) src = Wv + (size_t)(row-  50) * HIDN;
    else if (row < 1588) src = Bq + (size_t)(row-  52) * HIDN;
    else if (row < 2100) src = Bk + (size_t)(row-1588) * HIDN;
    else if (row < 2612) src = Bv + (size_t)(row-2100) * HIDN;
  } else {
    dst = Wob + (size_t)(row - NPAD) * HIDN;
    src = Wo + (size_t)(row - NPAD) * HIDN;
  }
  bf16x8 o;
  if (src) {
    const float4* p = reinterpret_cast<const float4*>(src + c);
    float4 a = p[0], b = p[1];
    o[0]=(bf16)a.x; o[1]=(bf16)a.y; o[2]=(bf16)a.z; o[3]=(bf16)a.w;
    o[4]=(bf16)b.x; o[5]=(bf16)b.y; o[6]=(bf16)b.z; o[7]=(bf16)b.w;
  } else {
    #pragma unroll
    for (int j = 0; j < 8; ++j) o[j] = (bf16)0.f;
  }
  *reinterpret_cast<bf16x8*>(dst + c) = o;
}

// ---------------------------------------------------------------- GEMM (B^T input)
// C[m][n] = sum_k A[m][k] * Bt[n][k].  128x128 tile, BK=64, 4 waves (2x2).
// T3 2-phase + rule-#21 both-sides swizzle (unchanged from R6).
__launch_bounds__(256)
__global__ void gemm_bt_kernel(const bf16* __restrict__ A, const bf16* __restrict__ Bt,
                               float* __restrict__ C, int K, int N) {
  __shared__ __align__(16) bf16 As[2][128 * 64];
  __shared__ __align__(16) bf16 Bs[2][128 * 64];
  const int t = threadIdx.x;
  const int lane = t & 63, wid = t >> 6;
  const int g = lane >> 4, c16 = lane & 15;
  const int nwg = (int)(gridDim.x * gridDim.y);
  int flat = (int)(blockIdx.y * gridDim.x + blockIdx.x);
  flat = (flat & 7) * (nwg >> 3) + (flat >> 3);            // XCD swizzle
  const int bxs = flat % (int)gridDim.x, bys = flat / (int)gridDim.x;
  const int rowA0 = bys * 128, rowB0 = bxs * 128;
  const int wrow = (wid >> 1) * 64, wcol = (wid & 1) * 64;
  const int srow = (lane >> 3), sunit = lane & 7;        // staging: 8 rows x 8 units
  const int sgx = (sunit ^ (srow & 7)) * 8;              // inverse-swizzled global col
  const int rswz = c16 & 7;                              // read-side swizzle key
  f32x4 z = {0.f, 0.f, 0.f, 0.f};
  f32x4 acc[4][4];
  #pragma unroll
  for (int m = 0; m < 4; ++m)
    #pragma unroll
    for (int n = 0; n < 4; ++n) acc[m][n] = z;

  auto stage = [&](int buf, int kt) {
    #pragma unroll
    for (int i = 0; i < 4; ++i) {                 // wave stages rows [wid*32, wid*32+32)
      int r0 = wid * 32 + i * 8;
      gload16(A + (size_t)(rowA0 + r0 + srow) * K + kt + sgx, &As[buf][r0 * 64]);
      gload16(Bt + (size_t)(rowB0 + r0 + srow) * K + kt + sgx, &Bs[buf][r0 * 64]);
    }
  };

  const int nk = K >> 6;
  stage(0, 0);
  __syncthreads();
  for (int ti = 0; ti < nk; ++ti) {
    const int cb = ti & 1;
    if (ti + 1 < nk) stage(cb ^ 1, (ti + 1) * 64);       // prefetch next K-tile
    #pragma unroll
    for (int ks = 0; ks < 2; ++ks) {
      bf16x8 af[4], bfr[4];
      #pragma unroll
      for (int m = 0; m < 4; ++m)
        af[m] = *reinterpret_cast<const bf16x8*>(
            &As[cb][(wrow + m*16 + c16) * 64 + ((ks*4 + g) ^ rswz) * 8]);
      #pragma unroll
      for (int n = 0; n < 4; ++n)
        bfr[n] = *reinterpret_cast<const bf16x8*>(
            &Bs[cb][(wcol + n*16 + c16) * 64 + ((ks*4 + g) ^ rswz) * 8]);
      __builtin_amdgcn_s_setprio(1);
      #pragma unroll
      for (int m = 0; m < 4; ++m)
        #pragma unroll
        for (int n = 0; n < 4; ++n)
          acc[m][n] = __builtin_amdgcn_mfma_f32_16x16x32_bf16(af[m], bfr[n], acc[m][n], 0, 0, 0);
      __builtin_amdgcn_s_setprio(0);
    }
    __syncthreads();                                     // drains prefetch (landed under MFMA)
  }
  #pragma unroll
  for (int m = 0; m < 4; ++m)
    #pragma unroll
    for (int n = 0; n < 4; ++n)
      #pragma unroll
      for (int r = 0; r < 4; ++r) {
        int row = rowA0 + wrow + m*16 + g*4 + r;   // C/D: row=(lane>>4)*4+reg
        int col = rowB0 + wcol + n*16 + c16;       //      col=lane&15
        C[(size_t)row * N + col] = acc[m][n][r];
      }
}

// ---------------------------------------------------------------- RoPE + rank contraction
__global__ void qkv_kernel(const float* __restrict__ P, const float* __restrict__ fcos,
                           const float* __restrict__ fsin, bf16* __restrict__ qat,
                           bf16* __restrict__ kat, bf16* __restrict__ vT) {
  const int m = blockIdx.x;
  const int b = m >> 11, s = m & 2047;
  const int d = threadIdx.x;
  __shared__ float Aq[48]; __shared__ float Ak[2]; __shared__ float Av[2];
  const float* Prow = P + (size_t)m * NPAD;
  if (d < 48) Aq[d] = Prow[d];
  else if (d < 50) Ak[d - 48] = Prow[d];
  else if (d < 52) Av[d - 50] = Prow[d];
  __syncthreads();
  const int dh = d & 127;
  const float co = fcos[s * 128 + dh], si = fsin[s * 128 + dh];
  const bool lo = (d < 128);
  float rq[6];
  #pragma unroll
  for (int r = 0; r < 6; ++r) {
    const float* Bq = Prow + 52 + r * 256;
    float x  = Bq[d];
    float xp = Bq[lo ? d + 128 : d - 128];
    rq[r] = lo ? (x * co - xp * si) : (xp * si + x * co);
  }
  #pragma unroll
  for (int h = 0; h < 8; ++h) {
    float a = 0.f;
    #pragma unroll
    for (int r = 0; r < 6; ++r) a += Aq[h * 6 + r] * rq[r];
    qat[((size_t)(b * 8 + h) * S_LEN + s) * DH + d] = (bf16)(a * QSCALE);
  }
  float ka = 0.f;
  #pragma unroll
  for (int r = 0; r < 2; ++r) {
    const float* Bk = Prow + 1588 + r * 256;
    float x  = Bk[d];
    float xp = Bk[lo ? d + 128 : d - 128];
    float rk = lo ? (x * co - xp * si) : (xp * si + x * co);
    ka += Ak[r] * rk;
  }
  kat[((size_t)b * S_LEN + s) * DH + d] = (bf16)(ka * 0.5f);
  float va = 0.f;
  #pragma unroll
  for (int r = 0; r < 2; ++r) va += Av[r] * Prow[2100 + r * 256 + d];
  vT[((size_t)b * DH + d) * S_LEN + s] = (bf16)(va * 0.5f);
}

// ---------------------------------------------------------------- flash attention v3
// 32-row waves + 32x32x16 MFMA (2x LDS-traffic reduction) + swapped QK^T so
// P stays in registers (pack via bf16 pairs + shfl_xor(32)).  Fixed-max
// softmax: p = exp(-100*rcp(exp(0.04x)+1)).  4 waves = 2 rowg x 2 hf,
// QBLK=64, KVBLK=64, single-buffered K/V (66KB -> 2 blocks/CU).  1-D grid
// 512: flats f and f+256 carry complementary qt (k, 31-k) so each CU's two
// resident blocks total a uniform 33 steps.
__launch_bounds__(256, 2)
__global__ void attn_kernel(const bf16* __restrict__ qat, const bf16* __restrict__ kat,
                            const bf16* __restrict__ vT, bf16* __restrict__ O) {
  const int f = (int)blockIdx.x;
  int qt, bh;
  if (f < 256) { qt = 31 - (f & 31); bh = f >> 5; }
  else         { int g2 = f - 256; qt = g2 & 31; bh = 8 + (g2 >> 5); }
  const int b = bh >> 3, h8 = bh & 7;
  const int t = threadIdx.x, lane = t & 63, w = t >> 6;
  const int l31 = lane & 31, hi = lane >> 5;
  const int rg = w >> 1, hf = w & 1;
  const int q0 = qt * 64;

  __shared__ __align__(16) bf16 Kb[64 * 256];    // 32 KB (reused as rg0 merge area)
  __shared__ __align__(16) bf16 Vb[256 * 64];    // 32 KB (reused as rg1 merge area)
  __shared__ float Lh[2][32];
  __shared__ float Li[2][32];

  const int qrow = q0 + rg * 32 + l31;           // this lane's global q row
  bf16x8 qf[16];                                 // Q[qrow][*] : 64 VGPR
  {
    const bf16* qp = qat + ((size_t)bh * S_LEN + qrow) * DH + hi * 8;
    #pragma unroll
    for (int kf = 0; kf < 16; ++kf)
      qf[kf] = *reinterpret_cast<const bf16x8*>(qp + kf * 16);
  }
  f32x16 acc[8];
  #pragma unroll
  for (int dt = 0; dt < 8; ++dt)
    #pragma unroll
    for (int e = 0; e < 16; ++e) acc[dt][e] = 0.f;
  float lsum = 0.f;

  const size_t kbase = (size_t)b * S_LEN * DH;
  const size_t vbase = (size_t)b * DH * S_LEN;
  const int krow_rd = hf * 32 + l31;             // K row this lane reads (QK A-op)
  const int kswz = l31 & 7;

  for (int ts = 0; ts <= qt; ++ts) {
    const int j0 = ts * 64;
    // ---- stage K[64][256] + V^T[256][64], swizzled source, linear dest ----
    #pragma unroll
    for (int i = 0; i < 8; ++i) {
      int kr = i * 8 + (t >> 5);                 // K row 0..63
      gload16(kat + kbase + (size_t)(j0 + kr) * DH + ((t & 31) ^ (kr & 7)) * 8,
              &Kb[(i * 256 + w * 64) * 8]);
      int vr = i * 32 + (t >> 3);                // V^T row 0..255
      gload16(vT + vbase + (size_t)vr * S_LEN + j0 + ((t & 7) ^ (vr & 7)) * 8,
              &Vb[(i * 256 + w * 64) * 8]);
    }
    __syncthreads();                             // staged data visible (vmcnt drained)

    // ---- QK^T swapped: D[kv][q] = K . Q^T  (two chains for dep-latency) ----
    f32x16 d0, d1;
    #pragma unroll
    for (int e = 0; e < 16; ++e) { d0[e] = 0.f; d1[e] = 0.f; }
    __builtin_amdgcn_s_setprio(1);
    #pragma unroll
    for (int kf = 0; kf < 16; kf += 2) {
      bf16x8 kb0 = *reinterpret_cast<const bf16x8*>(
          &Kb[krow_rd * 256 + (((kf << 1) | hi) ^ kswz) * 8]);
      d0 = __builtin_amdgcn_mfma_f32_32x32x16_bf16(kb0, qf[kf], d0, 0, 0, 0);
      bf16x8 kb1 = *reinterpret_cast<const bf16x8*>(
          &Kb[krow_rd * 256 + ((((kf + 1) << 1) | hi) ^ kswz) * 8]);
      d1 = __builtin_amdgcn_mfma_f32_32x32x16_bf16(kb1, qf[kf + 1], d1, 0, 0, 0);
    }
    __builtin_amdgcn_s_setprio(0);

    // ---- softcap + causal + fixed-max exp (P in registers) ----
    float p[16];
    #pragma unroll
    for (int r = 0; r < 16; ++r) {
      int kv = j0 + hf * 32 + (r & 3) + ((r >> 2) << 3) + (hi << 2);
      float x = d0[r] + d1[r];
      float pv = (kv <= qrow)
                   ? __expf(-100.f * __frcp_rn(__expf(x * 0.04f) + 1.f))
                   : 0.f;
      p[r] = pv;
      lsum += pv;
    }

    // ---- pack P -> PV A-frags via bf16 pairs + lane<->lane+32 exchange ----
    u32 own[8], sw[8];
    #pragma unroll
    for (int j = 0; j < 8; ++j) {
      unsigned short a = __builtin_bit_cast(unsigned short, (bf16)p[2 * j]);
      unsigned short c = __builtin_bit_cast(unsigned short, (bf16)p[2 * j + 1]);
      own[j] = (u32)a | ((u32)c << 16);
    }
    #pragma unroll
    for (int j = 0; j < 8; ++j) sw[j] = (u32)__shfl_xor((int)own[j], 32);
    u32x4 fa0 = hi ? u32x4{sw[2], sw[3], own[2], own[3]}
                   : u32x4{own[0], own[1], sw[0], sw[1]};
    u32x4 fa1 = hi ? u32x4{sw[6], sw[7], own[6], own[7]}
                   : u32x4{own[4], own[5], sw[4], sw[5]};
    bf16x8 pa0 = __builtin_bit_cast(bf16x8, fa0);
    bf16x8 pa1 = __builtin_bit_cast(bf16x8, fa1);

    // ---- PV: O[q][d] += P . V  (V^T rows as B-op) ----
    __builtin_amdgcn_s_setprio(1);
    #pragma unroll
    for (int dt = 0; dt < 8; ++dt) {
      int vrow = dt * 32 + l31;
      bf16x8 vb0 = *reinterpret_cast<const bf16x8*>(
          &Vb[vrow * 64 + (((hf << 2) | hi) ^ (vrow & 7)) * 8]);
      acc[dt] = __builtin_amdgcn_mfma_f32_32x32x16_bf16(pa0, vb0, acc[dt], 0, 0, 0);
      bf16x8 vb1 = *reinterpret_cast<const bf16x8*>(
          &Vb[vrow * 64 + (((hf << 2) | 2 | hi) ^ (vrow & 7)) * 8]);
      acc[dt] = __builtin_amdgcn_mfma_f32_32x32x16_bf16(pa1, vb1, acc[dt], 0, 0, 0);
    }
    __builtin_amdgcn_s_setprio(0);
    __syncthreads();                             // reads done before next stage
  }

  // ---- merge hf halves (LDS, reusing K/V buffers) + normalize + write O ----
  lsum += __shfl_xor(lsum, 32);                  // hi merge
  float* Fc = (rg == 0) ? (float*)Kb : (float*)Vb;   // 32KB = 32x256 f32 each
  if (hf == 1) {
    #pragma unroll
    for (int dt = 0; dt < 8; ++dt)
      #pragma unroll
      for (int r = 0; r < 16; ++r) {
        int ql = (r & 3) + ((r >> 2) << 3) + (hi << 2);
        Fc[ql * 256 + dt * 32 + l31] = acc[dt][r];
      }
    if (lane < 32) Lh[rg][l31] = lsum;
  }
  __syncthreads();
  if (hf == 0) {
    float ltot = lsum + Lh[rg][l31];
    if (lane < 32) Li[rg][l31] = 1.f / ltot;
    #pragma unroll
    for (int dt = 0; dt < 8; ++dt)
      #pragma unroll
      for (int r = 0; r < 16; ++r) {
        int ql = (r & 3) + ((r >> 2) << 3) + (hi << 2);
        float v = (acc[dt][r] + Fc[ql * 256 + dt * 32 + l31]) * Li[rg][ql];
        O[((size_t)b * S_LEN + q0 + rg * 32 + ql) * (size_t)(NH * DH) + h8 * DH +
          dt * 32 + l31] = (bf16)v;
      }
  }
}

// ---------------------------------------------------------------- launch
extern "C" void kernel_launch(void* const* d_in, const int* in_sizes, int n_in,
                              void* d_out, int out_size, void* d_ws, size_t ws_size,
                              hipStream_t stream) {
  (void)in_sizes; (void)n_in; (void)out_size; (void)ws_size;
  const float* hs   = (const float*)d_in[0];
  const float* fcos = (const float*)d_in[1];
  const float* fsin = (const float*)d_in[2];
  // d_in[3] mask (analytic causal), d_in[4] kv_write_indices (arange) -- unused
  const float* Wq = (const float*)d_in[5];
  const float* Wk = (const float*)d_in[6];
  const float* Wv = (const float*)d_in[7];
  const float* Bq = (const float*)d_in[8];
  const float* Bk = (const float*)d_in[9];
  const float* Bv = (const float*)d_in[10];
  const float* Wo = (const float*)d_in[11];

  char* ws = (char*)d_ws;
  size_t off = 0;
  auto alloc = [&](size_t bytes) {
    void* p = ws + off;
    off += (bytes + 255) & ~(size_t)255;
    return p;
  };
  bf16*  Xbf  = (bf16*) alloc((size_t)MTOT * HIDN * 2);           // 16.8 MB
  bf16*  Wcat = (bf16*) alloc((size_t)NPAD * HIDN * 2);           // 11.0 MB
  bf16*  Wob  = (bf16*) alloc((size_t)HIDN * HIDN * 2);           //  8.4 MB
  float* P    = (float*)alloc((size_t)MTOT * NPAD * 4);           // 44.0 MB
  bf16*  qat  = (bf16*) alloc((size_t)BATCH * NH * S_LEN * DH * 2); // 16.8 MB
  bf16*  kat  = (bf16*) alloc((size_t)BATCH * S_LEN * DH * 2);    //  2.1 MB
  bf16*  vT   = (bf16*) alloc((size_t)BATCH * DH * S_LEN * 2);    //  2.1 MB
  bf16*  Oat  = (bf16*) alloc((size_t)MTOT * NH * DH * 2);        // 16.8 MB
  float* out  = (float*)d_out;                                    // total ws ~118 MB

  cast_x_kernel<<<dim3(MTOT * HIDN / 8 / 256), dim3(256), 0, stream>>>(hs, Xbf);
  cast_w_kernel<<<dim3(NPAD + HIDN), dim3(256), 0, stream>>>(Wq, Wk, Wv, Bq, Bk, Bv, Wo, Wcat, Wob);
  gemm_bt_kernel<<<dim3(NPAD / 128, MTOT / 128), dim3(256), 0, stream>>>(Xbf, Wcat, P, HIDN, NPAD);
  qkv_kernel<<<dim3(MTOT), dim3(256), 0, stream>>>(P, fcos, fsin, qat, kat, vT);
  attn_kernel<<<dim3(512), dim3(256), 0, stream>>>(qat, kat, vT, Oat);
  gemm_bt_kernel<<<dim3(HIDN / 128, MTOT / 128), dim3(256), 0, stream>>>(Oat, Wob, out, HIDN, HIDN);
}